// Round 2
// baseline (14607.924 us; speedup 1.0000x reference)
//
#include <hip/hip_runtime.h>

#define T_STEPS 1000
#define BATCH   256
#define NIN     128
#define NHID    512
#define NOUT    128
#define SLOT    (BATCH * NHID)   // 131072 halves = 256 KiB per ring slot
#define NBLK    32               // persistent blocks (1 per CU, trivially co-resident)

typedef _Float16 half8    __attribute__((ext_vector_type(8)));
typedef float    floatx4  __attribute__((ext_vector_type(4)));
typedef float    floatx16 __attribute__((ext_vector_type(16)));

__device__ __forceinline__ half8 f8_to_h8(const float* __restrict__ p) {
  floatx4 lo = *(const floatx4*)p;
  floatx4 hi = *(const floatx4*)(p + 4);
  half8 r;
#pragma unroll
  for (int i = 0; i < 4; ++i) { r[i] = (_Float16)lo[i]; r[i + 4] = (_Float16)hi[i]; }
  return r;
}

// -------- init: zero barrier counter + ring slot 0 (s_{-1} = 0) -------------
__global__ void init_ws_kernel(unsigned int* counter, _Float16* slots) {
  size_t idx = (size_t)blockIdx.x * blockDim.x + threadIdx.x;  // 64*256=16384
  ((int4*)slots)[idx] = make_int4(0, 0, 0, 0);                 // 16384*16B = 256 KiB
  if (idx == 0) *counter = 0u;
}

// ---------------- persistent fused kernel: 32 blocks x 256 thr --------------
// Recurrence: per wave one 32x32 tile of [B=256, H=512].
//   mfma_f32_32x32x16_f16 A-frag: row=lane&31, k=(lane>>5)*8+j per 16-chunk.
//   C/D: col=lane&31, row=(reg&3)+8*(reg>>2)+4*(lane>>5).
// Readout: per wave one 16x16 tile of out[B=256, O=128] via mfma_f32_16x16x32_f16.
//   A/B frag: row=lane&15, k=(lane>>4)*8+j per 32-chunk. C/D: col=lane&15, row=(lane>>4)*4+reg.
__global__ __launch_bounds__(256, 1) void bnn_persistent_kernel(
    const float* __restrict__ X,     // [T,B,NIN]
    const float* __restrict__ Win,   // [NHID,NIN]
    const float* __restrict__ bin,   // [NHID]
    const float* __restrict__ Wrec,  // [NHID,NHID]
    const float* __restrict__ Wout,  // [NOUT,NHID]
    const float* __restrict__ bout,  // [NOUT]
    float* __restrict__ out,         // [T,B,NOUT]
    _Float16* __restrict__ slots,    // 2 * SLOT fp16 ring
    unsigned int* __restrict__ counter)
{
  const int tid = threadIdx.x;
  const int l   = tid & 63;
  const int w   = tid >> 6;
  const int ln  = l & 31;
  const int lk  = (l >> 5) * 8;
  const int bi  = blockIdx.x & 3;   // batch-tile  (4 x 64 = 256)
  const int bj  = blockIdx.x >> 2;  // hidden-tile (8 x 64 = 512)
  const int m0  = bi * 64 + (w & 1) * 32;
  const int n0  = bj * 64 + (w >> 1) * 32;

  // ---- resident weight fragments (converted f32 -> fp16 once) ----
  half8 wr[32];
#pragma unroll
  for (int kk = 0; kk < 32; ++kk)
    wr[kk] = f8_to_h8(Wrec + (size_t)(n0 + ln) * NHID + kk * 16 + lk);
  half8 wi[8];
#pragma unroll
  for (int kk = 0; kk < 8; ++kk)
    wi[kk] = f8_to_h8(Win + (size_t)(n0 + ln) * NIN + kk * 16 + lk);
  const float binv = bin[n0 + ln];

  // ---- readout tile assignment: 128 tiles of 16x16 over [256 x 128] ----
  const int tile = blockIdx.x * 4 + w;    // 0..127
  const int mo   = (tile >> 3) * 16;      // batch rows
  const int no   = (tile & 7) * 16;       // out cols
  const int l16  = l & 15;
  const int q    = l >> 4;                // quad 0..3
  half8 wo[16];
#pragma unroll
  for (int kk = 0; kk < 16; ++kk)
    wo[kk] = f8_to_h8(Wout + (size_t)(no + l16) * NHID + kk * 32 + q * 8);
  const float bo = bout[no + l16];

  // ---- GLIFR state in registers (C-layout positions) ----
  float v[16], a0[16], a1[16], sp[16];
#pragma unroll
  for (int r = 0; r < 16; ++r) { v[r] = 0.f; a0[r] = 0.f; a1[r] = 0.f; sp[r] = 0.f; }

  const int   mbase = m0 + 4 * (l >> 5);
  const float C_VI  = (float)(0.05 * 0.2 * (0.1 + 1.0 / 512.0));  // DT*K_M*R_HID

  for (int t = 0; t <= T_STEPS; ++t) {
    // ---- input projection for s_t (barrier-independent prefetch) ----
    floatx16 acc;
    if (t < T_STEPS) {
      const float* xt = X + (size_t)t * (BATCH * NIN) + (size_t)(m0 + ln) * NIN + lk;
      half8 ax[8];
#pragma unroll
      for (int kk = 0; kk < 8; ++kk) ax[kk] = f8_to_h8(xt + kk * 16);
#pragma unroll
      for (int i = 0; i < 16; ++i) acc[i] = binv;
#pragma unroll
      for (int kk = 0; kk < 8; ++kk)
        acc = __builtin_amdgcn_mfma_f32_32x32x16_f16(ax[kk], wi[kk], acc, 0, 0, 0);
    }

    // ---- grid barrier #t: all s_{t-1} stores globally visible ----
    __syncthreads();                        // drains this block's stores/loads
    if (tid == 0) {
      __threadfence();                      // release (L2 writeback, agent scope)
      atomicAdd(counter, 1u);               // device-scope by default
      const unsigned int tgt = (unsigned int)NBLK * (unsigned int)(t + 1);
      while (__hip_atomic_load(counter, __ATOMIC_RELAXED, __HIP_MEMORY_SCOPE_AGENT) < tgt)
        __builtin_amdgcn_s_sleep(2);
    }
    __syncthreads();
    __threadfence();                        // acquire (invalidate stale L2 lines)

    const _Float16* Sprev = slots + (size_t)(t & 1) * SLOT;   // holds s_{t-1}

    // ---- recurrence + GLIFR update; write s_t into the other slot ----
    if (t < T_STEPS) {
#pragma unroll
      for (int kk = 0; kk < 32; ++kk) {
        half8 as = *(const half8*)(Sprev + (size_t)(m0 + ln) * NHID + kk * 16 + lk);
        acc = __builtin_amdgcn_mfma_f32_32x32x16_f16(as, wr[kk], acc, 0, 0, 0);
      }
      _Float16* Scur = slots + (size_t)((t + 1) & 1) * SLOT;
#pragma unroll
      for (int r = 0; r < 16; ++r) {
        const float y  = 0.5f * acc[r];                  // avg of the 2 inputs
        a0[r] = a0[r] * 0.85f - 0.05f * sp[r];           // 1-DT*3,   DT*1*(-1)
        a1[r] = a1[r] * -0.5f - 0.05f * sp[r];           // 1-DT*30,  DT*(-1)*1
        const float it = y + a0[r] + a1[r] + 700.0f;     // + I0
        v[r] = v[r] * 0.99f * (1.0f - 0.05f * sp[r]) + C_VI * it;
        const float s = 20.0f / (1.0f + __expf(-0.02f * v[r]));  // 20*sigmoid(v/50)
        sp[r] = s;
        const int m = mbase + (r & 3) + 8 * (r >> 2);
        Scur[(size_t)m * NHID + n0 + ln] = (_Float16)s;
      }
    }

    // ---- readout of out_{t-1} = s_{t-1} @ Wout.T + bout (off critical path) ----
    if (t >= 1) {
      floatx4 oacc;
#pragma unroll
      for (int r = 0; r < 4; ++r) oacc[r] = bo;
#pragma unroll
      for (int kk = 0; kk < 16; ++kk) {
        half8 a = *(const half8*)(Sprev + (size_t)(mo + l16) * NHID + kk * 32 + q * 8);
        oacc = __builtin_amdgcn_mfma_f32_16x16x32_f16(a, wo[kk], oacc, 0, 0, 0);
      }
      float* op = out + ((size_t)(t - 1) * BATCH + mo) * NOUT + no;
#pragma unroll
      for (int r = 0; r < 4; ++r)
        op[(size_t)(q * 4 + r) * NOUT + l16] = oacc[r];
    }
  }
}

extern "C" void kernel_launch(void* const* d_in, const int* in_sizes, int n_in,
                              void* d_out, int out_size, void* d_ws, size_t ws_size,
                              hipStream_t stream) {
  const float* X    = (const float*)d_in[0];
  const float* Win  = (const float*)d_in[1];
  const float* bin  = (const float*)d_in[2];
  const float* Wrec = (const float*)d_in[3];
  const float* Wout = (const float*)d_in[4];
  const float* bout = (const float*)d_in[5];
  float* out = (float*)d_out;

  unsigned int* counter = (unsigned int*)d_ws;
  _Float16* slots = (_Float16*)((char*)d_ws + 1024);   // 2 slots = 512 KiB

  hipLaunchKernelGGL(init_ws_kernel, dim3(64), dim3(256), 0, stream, counter, slots);
  hipLaunchKernelGGL(bnn_persistent_kernel, dim3(NBLK), dim3(256), 0, stream,
                     X, Win, bin, Wrec, Wout, bout, out, slots, counter);
}